// Round 4
// baseline (402.889 us; speedup 1.0000x reference)
//
#include <hip/hip_runtime.h>

// CrossMerge3D: out[b,c,i,j,k] = (sum of 12 scan contributions)/12
// B=2, S=12, C=96, D=32, N=32768.
// group-i (s=0..3):  n = i*1024 + j*32 + k ; y0[n]+y1[n]+y2[N-1-n]+y3[N-1-n]
// group-j (s=4..7):  n = j*1024 + k*32 + i ; y4[n]+y5[n]+y6[N-1-n]+y7[N-1-n]
// group-k (s=8..11): n = k*1024 + i*32 + j ; y8[n]+y9[n]+y10[N-1-n]+y11[N-1-n]
//
// v4: 2 blocks per (b,c), split along i (i-half h). 384 blocks x 512 threads,
// LDS 67.6 KB -> 2 blocks/CU co-resident (hides the per-phase barrier drain
// that a 1-block/CU 135 KB version cannot). All 256 CUs occupied (was 192).
// Split on i: group-i reads (i slow) contiguous, group-k reads (i mid) full
// 128B lines, output (i slow) contiguous; only group-j reads (i fast) drop to
// 64B granularity -- sibling blocks (h=0/1) consume complementary halves and
// are pinned to the same XCD by a chunked swizzle so L2 merges them.

#define C_ 96
#define N_ 32768
#define SCAN_STRIDE ((size_t)C_ * N_)

// LDS tile: i_loc in [0,16), strides k:1, j:33, i:1057 (all == 1 mod 32).
#define J_STR 33
#define I_STR 1057
#define LDS_FLOATS (15 * I_STR + 31 * J_STR + 31 + 1)  // 16910 -> 67640 bytes

__global__ void __launch_bounds__(512, 4)
cross_merge3d_kernel(const float* __restrict__ ys, float* __restrict__ out) {
    extern __shared__ float lds[];

    // Chunked XCD swizzle: HW round-robins blockIdx over 8 XCDs; map so each
    // XCD gets a contiguous chunk of 48 works -> sibling pairs share an XCD L2.
    const int work = (blockIdx.x & 7) * 48 + (blockIdx.x >> 3);
    const int h  = work & 1;         // i-half: i in [16h, 16h+16)
    const int bc = work >> 1;        // 0..191
    const int b  = bc / C_;
    const int c  = bc % C_;
    const float* y = ys + ((size_t)b * 12 * C_ + c) * (size_t)N_;
    const int t = threadIdx.x;

    // ---- Phase 1: group-j (scans 4..7), layout (j,k,i), fast dim = i
    {
        const float4* y4 = (const float4*)(y + 4 * SCAN_STRIDE);
        const float4* y5 = (const float4*)(y + 5 * SCAN_STRIDE);
        const float4* y6 = (const float4*)(y + 6 * SCAN_STRIDE);
        const float4* y7 = (const float4*)(y + 7 * SCAN_STRIDE);
        const int q4 = t & 3;             // float4 slot within our 16-float i-run
        const int kk = (t >> 2) & 31;
        const int hi = t >> 7;            // 0..3
        #pragma unroll 2
        for (int it = 0; it < 8; ++it) {
            const int jj = hi + 4 * it;
            const int v  = jj * 256 + kk * 8 + h * 4 + q4;  // i = 16h + 4q4 + e
            const int r  = 8191 - v;
            const float4 f0 = y4[v];
            const float4 f1 = y5[v];
            const float4 r0 = y6[r];      // mirrored float4, elems reversed
            const float4 r1 = y7[r];
            float* p = &lds[(4 * q4) * I_STR + jj * J_STR + kk];  // i_loc = 4q4+e
            p[0 * I_STR] = f0.x + f1.x + r0.w + r1.w;
            p[1 * I_STR] = f0.y + f1.y + r0.z + r1.z;
            p[2 * I_STR] = f0.z + f1.z + r0.y + r1.y;
            p[3 * I_STR] = f0.w + f1.w + r0.x + r1.x;
        }
    }
    __syncthreads();

    // ---- Phase 2: group-k (scans 8..11), layout (k,i,j), fast dim = j
    {
        const float4* y8  = (const float4*)(y + 8  * SCAN_STRIDE);
        const float4* y9  = (const float4*)(y + 9  * SCAN_STRIDE);
        const float4* y10 = (const float4*)(y + 10 * SCAN_STRIDE);
        const float4* y11 = (const float4*)(y + 11 * SCAN_STRIDE);
        const int q  = t & 7;             // float4 slot along j
        const int il = (t >> 3) & 15;     // i_loc
        const int hi = t >> 7;            // 0..3
        #pragma unroll 2
        for (int it = 0; it < 8; ++it) {
            const int kk = hi + 4 * it;
            const int v  = kk * 256 + (16 * h + il) * 8 + q;  // jj = 4q+e
            const int r  = 8191 - v;
            const float4 f0 = y8[v];
            const float4 f1 = y9[v];
            const float4 r0 = y10[r];
            const float4 r1 = y11[r];
            float* p = &lds[il * I_STR + (4 * q) * J_STR + kk];
            p[0 * J_STR] += f0.x + f1.x + r0.w + r1.w;
            p[1 * J_STR] += f0.y + f1.y + r0.z + r1.z;
            p[2 * J_STR] += f0.z + f1.z + r0.y + r1.y;
            p[3 * J_STR] += f0.w + f1.w + r0.x + r1.x;
        }
    }
    __syncthreads();

    // ---- Phase 3: group-i (scans 0..3) + output, layout (i,j,k), fast dim = k
    {
        const float4* y0 = (const float4*)(y + 0 * SCAN_STRIDE);
        const float4* y1 = (const float4*)(y + 1 * SCAN_STRIDE);
        const float4* y2 = (const float4*)(y + 2 * SCAN_STRIDE);
        const float4* y3 = (const float4*)(y + 3 * SCAN_STRIDE);
        float4* o4 = (float4*)(out + ((size_t)b * C_ + c) * (size_t)N_);
        const int q  = t & 7;             // float4 slot along k
        const int jj = (t >> 3) & 31;
        const int hi = t >> 8;            // 0..1
        #pragma unroll 2
        for (int it = 0; it < 8; ++it) {
            const int il = hi + 2 * it;   // i_loc 0..15
            const int v  = (16 * h + il) * 256 + jj * 8 + q;  // kk = 4q+e
            const int r  = 8191 - v;
            const float4 f0 = y0[v];
            const float4 f1 = y1[v];
            const float4 r0 = y2[r];
            const float4 r1 = y3[r];
            const float* p = &lds[il * I_STR + jj * J_STR + 4 * q];
            float4 res;
            res.x = (f0.x + f1.x + r0.w + r1.w + p[0]) * (1.0f / 12.0f);
            res.y = (f0.y + f1.y + r0.z + r1.z + p[1]) * (1.0f / 12.0f);
            res.z = (f0.z + f1.z + r0.y + r1.y + p[2]) * (1.0f / 12.0f);
            res.w = (f0.w + f1.w + r0.x + r1.x + p[3]) * (1.0f / 12.0f);
            o4[v] = res;
        }
    }
}

extern "C" void kernel_launch(void* const* d_in, const int* in_sizes, int n_in,
                              void* d_out, int out_size, void* d_ws, size_t ws_size,
                              hipStream_t stream) {
    (void)in_sizes; (void)n_in; (void)d_ws; (void)ws_size; (void)out_size;
    const float* ys = (const float*)d_in[0];
    float* out = (float*)d_out;

    const size_t lds_bytes = (size_t)LDS_FLOATS * sizeof(float);  // 67640 > 64K default
    hipFuncSetAttribute(reinterpret_cast<const void*>(&cross_merge3d_kernel),
                        hipFuncAttributeMaxDynamicSharedMemorySize, (int)lds_bytes);

    dim3 grid(2 * C_ * 2);   // 384 blocks: (b,c) x i-half
    dim3 block(512);
    cross_merge3d_kernel<<<grid, block, lds_bytes, stream>>>(ys, out);
}